// Round 7
// baseline (269.535 us; speedup 1.0000x reference)
//
#include <hip/hip_runtime.h>

// FilteredLReLU: up2(17-tap) -> *2 -> lrelu(0.01) -> down2(17-tap), fused.
// Sliding-window streaming: 32 outputs/thread, x in a 16-float ring
// (prefetch 1 chunk = 4 iters ahead), accumulators in a 12-float ring
// (first tap overwrites -> no zero-init), outputs stored as float4 as
// they complete. All ring indices compile-time (full unroll).
//
//   ge[m] = lrelu( sum_{j=0..8} fe[j]*x[m-4+j] )   if 0<=m<T else 0
//   go[m] = lrelu( sum_{j=0..7} fo[j]*x[m-3+j] )   if 0<=m<T else 0
//   z[t]  = sum_{j=0..8} de[j]*ge[t-4+j] + sum_{j=0..7} dd[j]*go[t-4+j]
// (UP gain of 2 folded into fe/fo.)  lrelu(v) == max(v, 0.01*v).

#define T_LEN 32768
#define R_OUT 32
#define TPR   (T_LEN / R_OUT)   // 1024 threads per row
#define NCHUNK ((R_OUT + 16) / 4)   // 12 float4 chunks of x per thread

__device__ __forceinline__ float lrelu(float v) {
    return fmaxf(v, 0.01f * v);
}

__device__ __forceinline__ float to_sgpr(float v) {
    return __int_as_float(__builtin_amdgcn_readfirstlane(__float_as_int(v)));
}

template <bool FAST>
__device__ __forceinline__ void compute_tile(
    const float* __restrict__ xrow, float* __restrict__ orow, int t,
    const float* fe, const float* fo, const float* de, const float* dd)
{
    float xr[16];    // ring: xv[i] = x[t-8+i] lives in xr[i & 15]
    float acc[12];   // ring: z[t+r] accumulates in acc[r % 12]

    // ---- preload chunks 0..2 (xv[0..11]) ----
    #pragma unroll
    for (int c = 0; c < 3; ++c) {
        if (FAST) {
            float4 v = *reinterpret_cast<const float4*>(xrow + t - 8 + 4 * c);
            xr[4 * c + 0] = v.x; xr[4 * c + 1] = v.y;
            xr[4 * c + 2] = v.z; xr[4 * c + 3] = v.w;
        } else {
            #pragma unroll
            for (int q = 0; q < 4; ++q) {
                int g = t - 8 + 4 * c + q;
                xr[4 * c + q] = (g >= 0 && g < T_LEN) ? xrow[g] : 0.0f;
            }
        }
    }

    #pragma unroll
    for (int ml = 0; ml < R_OUT + 8; ++ml) {
        // ---- prefetch chunk ml/4+3 (first needed at ml+4) ----
        if ((ml & 3) == 0 && (ml / 4 + 3) < NCHUNK) {
            const int c = ml / 4 + 3;
            if (FAST) {
                float4 v = *reinterpret_cast<const float4*>(xrow + t - 8 + 4 * c);
                xr[(4 * c + 0) & 15] = v.x; xr[(4 * c + 1) & 15] = v.y;
                xr[(4 * c + 2) & 15] = v.z; xr[(4 * c + 3) & 15] = v.w;
            } else {
                #pragma unroll
                for (int q = 0; q < 4; ++q) {
                    int g = t - 8 + 4 * c + q;
                    xr[(4 * c + q) & 15] = (g >= 0 && g < T_LEN) ? xrow[g] : 0.0f;
                }
            }
        }

        // ---- even intermediate ge at window ml ----
        {
            float ae = 0.0f;
            #pragma unroll
            for (int j = 0; j < 9; ++j)
                ae = fmaf(fe[j], xr[(ml + j) & 15], ae);
            float g = lrelu(ae);
            if (!FAST) {
                int m = t - 4 + ml;
                if (m < 0 || m >= T_LEN) g = 0.0f;   // dn conv zero-pads y
            }
            if (ml < R_OUT)
                acc[ml % 12] = de[0] * g;            // overwrite-init
            #pragma unroll
            for (int r = (ml - 8 < 0 ? 0 : ml - 8);
                 r < (ml < R_OUT ? ml : R_OUT); ++r)
                acc[r % 12] = fmaf(de[ml - r], g, acc[r % 12]);
        }

        // ---- odd intermediate go at window ml ----
        if (ml < R_OUT + 7) {
            float ao = 0.0f;
            #pragma unroll
            for (int j = 0; j < 8; ++j)
                ao = fmaf(fo[j], xr[(ml + 1 + j) & 15], ao);
            float h = lrelu(ao);
            if (!FAST) {
                int m = t - 4 + ml;
                if (m < 0 || m >= T_LEN) h = 0.0f;
            }
            #pragma unroll
            for (int r = (ml - 7 < 0 ? 0 : ml - 7);
                 r <= (ml < R_OUT - 1 ? ml : R_OUT - 1); ++r)
                acc[r % 12] = fmaf(dd[ml - r], h, acc[r % 12]);
        }

        // ---- store 4 completed outputs (r = ml-11 .. ml-8) ----
        if (ml >= 11 && ((ml - 11) & 3) == 0) {
            const int r0 = ml - 11;
            *reinterpret_cast<float4*>(orow + t + r0) =
                make_float4(acc[(r0 + 0) % 12], acc[(r0 + 1) % 12],
                            acc[(r0 + 2) % 12], acc[(r0 + 3) % 12]);
        }
    }
}

__global__ __launch_bounds__(256, 4) void flrelu_ring(
    const float* __restrict__ x,
    const float* __restrict__ up,
    const float* __restrict__ dn,
    float* __restrict__ out)
{
    const int gid = blockIdx.x * 256 + threadIdx.x;
    const int row = gid >> 10;                 // / TPR
    const int t   = (gid & (TPR - 1)) * R_OUT;
    const float* __restrict__ xrow = x + (size_t)row * T_LEN;
    float* __restrict__ orow       = out + (size_t)row * T_LEN;

    // Taps -> SGPRs (wave-uniform). UP gain folded into fe/fo.
    float fe[9], fo[8], de[9], dd[8];
    #pragma unroll
    for (int j = 0; j < 9; ++j) {
        fe[j] = to_sgpr(2.0f * up[2 * j]);
        de[j] = to_sgpr(dn[2 * j]);
    }
    #pragma unroll
    for (int j = 0; j < 8; ++j) {
        fo[j] = to_sgpr(2.0f * up[2 * j + 1]);
        dd[j] = to_sgpr(dn[2 * j + 1]);
    }

    if (t >= 8 && t + R_OUT + 8 <= T_LEN) {
        compute_tile<true>(xrow, orow, t, fe, fo, de, dd);
    } else {
        compute_tile<false>(xrow, orow, t, fe, fo, de, dd);
    }
}

extern "C" void kernel_launch(void* const* d_in, const int* in_sizes, int n_in,
                              void* d_out, int out_size, void* d_ws, size_t ws_size,
                              hipStream_t stream) {
    const float* x  = (const float*)d_in[0];
    const float* up = (const float*)d_in[1];
    const float* dn = (const float*)d_in[2];
    float* out      = (float*)d_out;

    const int rows    = in_sizes[0] / T_LEN;         // 2048
    const int threads = rows * TPR;                  // 2.10M
    flrelu_ring<<<threads / 256, 256, 0, stream>>>(x, up, dn, out);
}

// Round 9
// 136.913 us; speedup vs baseline: 1.9687x; 1.9687x over previous
//
#include <hip/hip_runtime.h>
#include <stdint.h>

// FilteredLReLU: up2(17-tap) -> *2 -> lrelu(0.01) -> down2(17-tap), fused.
// f16 dot2 streaming version: v_dot2_f32_f16 does 2 MACs/instr with f32
// accumulate. Tolerance is 0.209 absolute (bf16-grade) -> f16 products are
// far more than accurate enough (abs err ~1e-2).
//
//   ge[m] = lrelu( sum_{j=0..8} fe[j]*x[m-4+j] )
//   go[m] = lrelu( sum_{j=0..7} fo[j]*x[m-3+j] )
//   z[t]  = sum_{j=0..8} de[j]*ge[t-4+j] + sum_{j=0..7} dd[j]*go[t-4+j]
// (UP gain of 2 folded into fe/fo.)
//
// Packing: xa[k]=(xv[2k],xv[2k+1]), xs[k]=(xv[2k+1],xv[2k+2]) f16 pairs;
// window conv = 5 (even) / 4 (odd) dot2; scatter packs (ge,go) against
// tap pairs dp[j]=(de[j],dd[j]) (dp[8]=(de[8],0)) = 9 dot2 per window.

#define T_LEN 32768
#define R_OUT 16
#define TPR   (T_LEN / R_OUT)   // 2048 threads per row

typedef __fp16 h16x2 __attribute__((ext_vector_type(2)));

__device__ __forceinline__ uint32_t pkrtz(float lo, float hi) {
    h16x2 p = __builtin_amdgcn_cvt_pkrtz(lo, hi);
    return __builtin_bit_cast(uint32_t, p);
}

__device__ __forceinline__ float fdot2(uint32_t a, uint32_t b, float c) {
    return __builtin_amdgcn_fdot2(__builtin_bit_cast(h16x2, a),
                                  __builtin_bit_cast(h16x2, b), c, false);
}

__device__ __forceinline__ float lrelu(float v) {
    return fmaxf(v, 0.01f * v);
}

__device__ __forceinline__ uint32_t rfl(uint32_t v) {
    return __builtin_amdgcn_readfirstlane(v);
}

__global__ __launch_bounds__(256, 4) void flrelu_dot2(
    const float* __restrict__ x,
    const float* __restrict__ up,
    const float* __restrict__ dn,
    float* __restrict__ out)
{
    const int gid = blockIdx.x * 256 + threadIdx.x;
    const int row = gid >> 11;                 // / TPR
    const int t   = (gid & (TPR - 1)) * R_OUT;
    const float* __restrict__ xrow = x + (size_t)row * T_LEN;
    float* __restrict__ orow       = out + (size_t)row * T_LEN;

    // f32 taps (uniform). UP gain folded into fe/fo.
    float fe[9], fo[8], de[9], dd[8];
    #pragma unroll
    for (int j = 0; j < 9; ++j) { fe[j] = 2.0f * up[2 * j]; de[j] = dn[2 * j]; }
    #pragma unroll
    for (int j = 0; j < 8; ++j) { fo[j] = 2.0f * up[2 * j + 1]; dd[j] = dn[2 * j + 1]; }

    if (t >= 8 && t + R_OUT + 8 <= T_LEN) {
        // ---------------- fast f16-dot2 path (interior) ----------------
        // packed taps -> SGPRs (wave-uniform)
        uint32_t fep[5], fop[4], dp[9];
        #pragma unroll
        for (int q = 0; q < 4; ++q) fep[q] = rfl(pkrtz(fe[2 * q], fe[2 * q + 1]));
        fep[4] = rfl(pkrtz(fe[8], 0.0f));
        #pragma unroll
        for (int q = 0; q < 4; ++q) fop[q] = rfl(pkrtz(fo[2 * q], fo[2 * q + 1]));
        #pragma unroll
        for (int j = 0; j < 8; ++j) dp[j] = rfl(pkrtz(de[j], dd[j]));
        dp[8] = rfl(pkrtz(de[8], 0.0f));

        // load x[t-8 .. t+23]
        float xv[32];
        const float4* xp = reinterpret_cast<const float4*>(xrow + t - 8);
        #pragma unroll
        for (int k = 0; k < 8; ++k) {
            float4 v = xp[k];
            xv[4 * k + 0] = v.x; xv[4 * k + 1] = v.y;
            xv[4 * k + 2] = v.z; xv[4 * k + 3] = v.w;
        }

        // f16 pairs: aligned + shifted-by-1
        uint32_t xa[16], xs[16];
        #pragma unroll
        for (int k = 0; k < 16; ++k) xa[k] = pkrtz(xv[2 * k], xv[2 * k + 1]);
        #pragma unroll
        for (int k = 0; k < 15; ++k)
            xs[k] = (xa[k] >> 16) | (xa[k + 1] << 16);   // v_alignbit_b32
        xs[15] = xa[15] >> 16;                            // (xv[31], 0)

        float acc[R_OUT];

        #pragma unroll
        for (int ml = 0; ml < R_OUT + 8; ++ml) {
            const int e = ml / 2;
            // even intermediate: fe[0..8] * xv[ml..ml+8]
            float ae;
            if ((ml & 1) == 0) {
                ae = fdot2(fep[0], xa[e], 0.0f);
                ae = fdot2(fep[1], xa[e + 1], ae);
                ae = fdot2(fep[2], xa[e + 2], ae);
                ae = fdot2(fep[3], xa[e + 3], ae);
                ae = fdot2(fep[4], xa[e + 4], ae);
            } else {
                ae = fdot2(fep[0], xs[e], 0.0f);
                ae = fdot2(fep[1], xs[e + 1], ae);
                ae = fdot2(fep[2], xs[e + 2], ae);
                ae = fdot2(fep[3], xs[e + 3], ae);
                ae = fdot2(fep[4], xs[e + 4], ae);
            }
            float g = lrelu(ae);

            // odd intermediate: fo[0..7] * xv[ml+1..ml+8]
            float h = 0.0f;
            if (ml < R_OUT + 7) {
                float ao;
                if ((ml & 1) == 0) {
                    ao = fdot2(fop[0], xs[e], 0.0f);
                    ao = fdot2(fop[1], xs[e + 1], ao);
                    ao = fdot2(fop[2], xs[e + 2], ao);
                    ao = fdot2(fop[3], xs[e + 3], ao);
                } else {
                    ao = fdot2(fop[0], xa[e + 1], 0.0f);
                    ao = fdot2(fop[1], xa[e + 2], ao);
                    ao = fdot2(fop[2], xa[e + 3], ao);
                    ao = fdot2(fop[3], xa[e + 4], ao);
                }
                h = lrelu(ao);
            }

            // scatter: acc[r] += de[ml-r]*g + dd[ml-r]*h  (dd[8] == 0 pad)
            const uint32_t p = pkrtz(g, h);
            #pragma unroll
            for (int r = 0; r < R_OUT; ++r) {
                if (r >= ml - 8 && r <= ml) {
                    if (r == ml)
                        acc[r] = fdot2(dp[0], p, 0.0f);     // overwrite-init
                    else
                        acc[r] = fdot2(dp[ml - r], p, acc[r]);
                }
            }
        }

        float4* op = reinterpret_cast<float4*>(orow + t);
        #pragma unroll
        for (int k = 0; k < R_OUT / 4; ++k)
            op[k] = make_float4(acc[4 * k + 0], acc[4 * k + 1],
                                acc[4 * k + 2], acc[4 * k + 3]);
    } else {
        // ---------------- scalar f32 boundary path ----------------
        float xv[R_OUT + 16];
        #pragma unroll
        for (int i = 0; i < R_OUT + 16; ++i) {
            int g = t - 8 + i;
            xv[i] = (g >= 0 && g < T_LEN) ? xrow[g] : 0.0f;
        }
        float acc[R_OUT];
        #pragma unroll
        for (int r = 0; r < R_OUT; ++r) acc[r] = 0.0f;

        #pragma unroll
        for (int ml = 0; ml < R_OUT + 8; ++ml) {
            float ae = 0.0f;
            #pragma unroll
            for (int j = 0; j < 9; ++j) ae = fmaf(fe[j], xv[ml + j], ae);
            float g = lrelu(ae);
            int m = t - 4 + ml;
            if (m < 0 || m >= T_LEN) g = 0.0f;   // dn conv zero-pads y
            #pragma unroll
            for (int r = 0; r < R_OUT; ++r)
                if (r >= ml - 8 && r <= ml)
                    acc[r] = fmaf(de[ml - r], g, acc[r]);

            if (ml < R_OUT + 7) {
                float ao = 0.0f;
                #pragma unroll
                for (int j = 0; j < 8; ++j) ao = fmaf(fo[j], xv[ml + 1 + j], ao);
                float h = lrelu(ao);
                if (m < 0 || m >= T_LEN) h = 0.0f;
                #pragma unroll
                for (int r = 0; r < R_OUT; ++r)
                    if (r >= ml - 7 && r <= ml)
                        acc[r] = fmaf(dd[ml - r], h, acc[r]);
            }
        }

        float4* op = reinterpret_cast<float4*>(orow + t);
        #pragma unroll
        for (int k = 0; k < R_OUT / 4; ++k)
            op[k] = make_float4(acc[4 * k + 0], acc[4 * k + 1],
                                acc[4 * k + 2], acc[4 * k + 3]);
    }
}

extern "C" void kernel_launch(void* const* d_in, const int* in_sizes, int n_in,
                              void* d_out, int out_size, void* d_ws, size_t ws_size,
                              hipStream_t stream) {
    const float* x  = (const float*)d_in[0];
    const float* up = (const float*)d_in[1];
    const float* dn = (const float*)d_in[2];
    float* out      = (float*)d_out;

    const int rows    = in_sizes[0] / T_LEN;         // 2048
    const int threads = rows * TPR;                  // 4.19M
    flrelu_dot2<<<threads / 256, 256, 0, stream>>>(x, up, dn, out);
}